// Round 3
// baseline (275.239 us; speedup 1.0000x reference)
//
#include <hip/hip_runtime.h>

typedef __bf16 bf16x8 __attribute__((ext_vector_type(8)));
typedef __bf16 bf16x4 __attribute__((ext_vector_type(4)));
typedef float  f32x4  __attribute__((ext_vector_type(4)));

#define GLDS16(g, l) __builtin_amdgcn_global_load_lds( \
    (const __attribute__((address_space(1))) void*)(g), \
    (__attribute__((address_space(3))) void*)(l), 16, 0, 0)

// ---------------- graph prep ----------------

__global__ void count_kernel(const int* __restrict__ dst, int* __restrict__ cnt, int E) {
  int idx = blockIdx.x * blockDim.x + threadIdx.x;
  int stride = gridDim.x * blockDim.x;
  for (int e = idx; e < E; e += stride) atomicAdd(&cnt[dst[e]], 1);
}

__global__ void dinv_kernel(const int* __restrict__ cnt, float* __restrict__ dinv, int n) {
  int i = blockIdx.x * blockDim.x + threadIdx.x;
  if (i < n) dinv[i] = rsqrtf((float)cnt[i] + 1.0f);
}

__global__ __launch_bounds__(1024) void scan_kernel(const int* __restrict__ cnt,
                                                    int* __restrict__ rowptr, int n) {
  __shared__ int part[1024];
  int t = threadIdx.x;
  int CH = (n + 1023) >> 10;
  int base = t * CH;
  int s = 0;
  for (int j = 0; j < CH; j++) { int k = base + j; if (k < n) s += cnt[k]; }
  part[t] = s;
  __syncthreads();
  for (int off = 1; off < 1024; off <<= 1) {
    int v = (t >= off) ? part[t - off] : 0;
    __syncthreads();
    part[t] += v;
    __syncthreads();
  }
  int run = (t == 0) ? 0 : part[t - 1];
  for (int j = 0; j < CH; j++) { int k = base + j; if (k < n) { rowptr[k] = run; run += cnt[k]; } }
  if (t == 0) rowptr[n] = part[1023];
}

// packed CSR entry: .x = src index, .y = coef bits
__global__ void fill_kernel(const int* __restrict__ src, const int* __restrict__ dst,
                            const int* __restrict__ rowptr, int* __restrict__ cur,
                            const float* __restrict__ dinv,
                            int2* __restrict__ csr_pack, int E) {
  int idx = blockIdx.x * blockDim.x + threadIdx.x;
  int stride = gridDim.x * blockDim.x;
  for (int e = idx; e < E; e += stride) {
    int s = src[e], d = dst[e];
    int slot = rowptr[d] + atomicAdd(&cur[d], 1);
    int2 p; p.x = s; p.y = __float_as_int(dinv[s] * dinv[d]);
    csr_pack[slot] = p;
  }
}

// ---------------- dtype prep ----------------

__global__ void f32_to_bf16_k(const float* __restrict__ in, __bf16* __restrict__ out, long n4) {
  long idx = (long)blockIdx.x * blockDim.x + threadIdx.x;
  long stride = (long)gridDim.x * blockDim.x;
  for (long i = idx; i < n4; i += stride) {
    float4 v = ((const float4*)in)[i];
    bf16x4 b;
    b[0] = (__bf16)v.x; b[1] = (__bf16)v.y; b[2] = (__bf16)v.z; b[3] = (__bf16)v.w;
    ((bf16x4*)out)[i] = b;
  }
}

// merged weight prep: w1t/w2t = transposed 512x512, wct = transposed concat [256][512]
__global__ void weights_prep(const float* __restrict__ W1, const float* __restrict__ W2,
                             const float* __restrict__ Wmu, const float* __restrict__ Wlv,
                             __bf16* __restrict__ w1t, __bf16* __restrict__ w2t,
                             __bf16* __restrict__ wct) {
  int id = blockIdx.x * blockDim.x + threadIdx.x;
  if (id < 262144) {
    int nn = id >> 9, kk = id & 511;
    w1t[id] = (__bf16)W1[kk * 512 + nn];
  } else if (id < 524288) {
    int t = id - 262144;
    int nn = t >> 9, kk = t & 511;
    w2t[t] = (__bf16)W2[kk * 512 + nn];
  } else if (id < 655360) {
    int t = id - 524288;
    int nn = t >> 9, kk = t & 511;       // nn 0..255
    float v = (nn < 128) ? Wmu[kk * 128 + nn] : Wlv[kk * 128 + (nn - 128)];
    wct[t] = (__bf16)v;
  }
}

// ---------------- GEMM: C[M,N] = A[M,K] @ Bt[N,K]^T  (bf16, f32 acc) ----------------
// 128x128 tile, BK=64, double-buffered LDS, counted vmcnt(8) across raw barriers.
// XOR granule swizzle (g ^= row&7): LDS linear dest, pre-swizzled GLOBAL source,
// matching swizzled ds_read (both-sides rule). 1D grid with bijective XCD chunking
// so blocks sharing an A row-panel land on the same XCD L2.

__global__ __launch_bounds__(256) void gemm_bt(const __bf16* __restrict__ A,
                                               const __bf16* __restrict__ Bt,
                                               __bf16* __restrict__ C,
                                               int M, int N, int K, int ntiles_n) {
  __shared__ __align__(16) __bf16 sA[2][128 * 64];
  __shared__ __align__(16) __bf16 sB[2][128 * 64];
  // bijective XCD remap (m204): xcd = orig%8 keeps dispatch's XCD; sub enumerates within
  const int nb = gridDim.x;
  const int orig = blockIdx.x;
  const int q = nb >> 3, r = nb & 7;
  const int xcd = orig & 7, sub = orig >> 3;
  const int pos = (xcd < r) ? (xcd * (q + 1) + sub) : (r * (q + 1) + (xcd - r) * q + sub);
  const int m0 = (pos / ntiles_n) * 128, n0 = (pos % ntiles_n) * 128;

  const int tid = threadIdx.x;
  const int wave = tid >> 6, lane = tid & 63;
  const int wr = wave >> 1, wc = wave & 1;
  f32x4 acc[4][4] = {};
  const int srow = lane >> 3;                 // row within 8-row chunk
  const int sg   = (lane & 7) ^ (srow & 7);   // pre-swizzled source granule (16B units)
  const int nt = K >> 6;

  auto STAGE = [&](int b, int k0) {
    #pragma unroll
    for (int c = 0; c < 4; ++c) {
      int chunk = wave * 4 + c;               // 0..15, 8 rows each
      int row = chunk * 8 + srow;
      int ga = m0 + row; if (ga >= M) ga = M - 1;
      GLDS16(A  + (long)ga * K         + k0 + sg * 8, sA[b] + chunk * 512);
      GLDS16(Bt + (long)(n0 + row) * K + k0 + sg * 8, sB[b] + chunk * 512);
    }
  };

  STAGE(0, 0);
  for (int t = 0; t < nt; ++t) {
    const int cur = t & 1;
    if (t + 1 < nt) {
      STAGE(cur ^ 1, (t + 1) << 6);
      asm volatile("s_waitcnt vmcnt(8)" ::: "memory");   // cur's 8 loads done, next 8 in flight
    } else {
      asm volatile("s_waitcnt vmcnt(0)" ::: "memory");
    }
    __builtin_amdgcn_s_barrier();
    __builtin_amdgcn_sched_barrier(0);

    const int fr = lane & 15, gbase = lane >> 4;
    bf16x8 af[4][2], bfr[4][2];
    #pragma unroll
    for (int mi = 0; mi < 4; mi++)
      #pragma unroll
      for (int ks = 0; ks < 2; ks++) {
        int row = wr * 64 + mi * 16 + fr;
        int gs = (ks * 4 + gbase) ^ (row & 7);
        af[mi][ks] = *(const bf16x8*)(sA[cur] + row * 64 + gs * 8);
      }
    #pragma unroll
    for (int ni = 0; ni < 4; ni++)
      #pragma unroll
      for (int ks = 0; ks < 2; ks++) {
        int row = wc * 64 + ni * 16 + fr;
        int gs = (ks * 4 + gbase) ^ (row & 7);
        bfr[ni][ks] = *(const bf16x8*)(sB[cur] + row * 64 + gs * 8);
      }
    #pragma unroll
    for (int mi = 0; mi < 4; mi++)
      #pragma unroll
      for (int ni = 0; ni < 4; ni++) {
        acc[mi][ni] = __builtin_amdgcn_mfma_f32_16x16x32_bf16(af[mi][0], bfr[ni][0], acc[mi][ni], 0, 0, 0);
        acc[mi][ni] = __builtin_amdgcn_mfma_f32_16x16x32_bf16(af[mi][1], bfr[ni][1], acc[mi][ni], 0, 0, 0);
      }
    asm volatile("s_waitcnt lgkmcnt(0)" ::: "memory");   // my ds_reads done before others restage
    __builtin_amdgcn_sched_barrier(0);
    __builtin_amdgcn_s_barrier();
  }

  const int crow0 = (lane >> 4) * 4, ccol = lane & 15;
  #pragma unroll
  for (int mi = 0; mi < 4; mi++)
    #pragma unroll
    for (int ni = 0; ni < 4; ni++)
      #pragma unroll
      for (int r2 = 0; r2 < 4; r2++) {
        int row = m0 + wr * 64 + mi * 16 + crow0 + r2;
        if (row < M)
          C[(long)row * N + n0 + wc * 64 + ni * 16 + ccol] = (__bf16)acc[mi][ni][r2];
      }
}

// ---------------- propagation: out = agg + self*h + b, fused epilogues ----------------
// One wave per node (direct map), 8-deep batched gather, packed (src,coef) metadata.
// MODE 0: relu + L2-normalize -> bf16 ; MODE 1: relu -> bf16 ; MODE 2: mu/lv/z -> f32

template<int EPL> struct VSel;
template<> struct VSel<8> { typedef bf16x8 T; };
template<> struct VSel<4> { typedef bf16x4 T; };

template<int EPL, int MODE>
__global__ __launch_bounds__(512) void prop_kernel(
    const __bf16* __restrict__ Cin, const int* __restrict__ rowptr,
    const int2* __restrict__ csr_pack,
    const float* __restrict__ dinv, const float* __restrict__ bias,
    const float* __restrict__ bmu, const float* __restrict__ blv,
    const float* __restrict__ eps,
    __bf16* __restrict__ hout, float* __restrict__ zout, int n) {
  constexpr int F = EPL * 64;
  typedef typename VSel<EPL>::T VecT;
  const int lane = threadIdx.x & 63;
  const int i = blockIdx.x * (blockDim.x >> 6) + (threadIdx.x >> 6);
  if (i >= n) return;
  const __bf16* __restrict__ Clane = Cin + lane * EPL;

  float acc[EPL];
  {
    const float di = dinv[i];
    const float sc = di * di;
    VecT v = *(const VecT*)(Clane + (size_t)i * F);
    #pragma unroll
    for (int j = 0; j < EPL; j++) acc[j] = sc * (float)v[j];
  }
  int e = rowptr[i];
  const int e1 = rowptr[i + 1];
  for (; e + 8 <= e1; e += 8) {
    int2 p[8];
    #pragma unroll
    for (int q = 0; q < 8; q++) p[q] = csr_pack[e + q];
    VecT v[8];
    #pragma unroll
    for (int q = 0; q < 8; q++) v[q] = *(const VecT*)(Clane + (size_t)p[q].x * F);
    #pragma unroll
    for (int q = 0; q < 8; q++) {
      float c = __int_as_float(p[q].y);
      #pragma unroll
      for (int j = 0; j < EPL; j++) acc[j] += c * (float)v[q][j];
    }
  }
  for (; e + 4 <= e1; e += 4) {
    int2 p[4];
    #pragma unroll
    for (int q = 0; q < 4; q++) p[q] = csr_pack[e + q];
    VecT v[4];
    #pragma unroll
    for (int q = 0; q < 4; q++) v[q] = *(const VecT*)(Clane + (size_t)p[q].x * F);
    #pragma unroll
    for (int q = 0; q < 4; q++) {
      float c = __int_as_float(p[q].y);
      #pragma unroll
      for (int j = 0; j < EPL; j++) acc[j] += c * (float)v[q][j];
    }
  }
  for (; e < e1; ++e) {
    int2 p = csr_pack[e];
    float c = __int_as_float(p.y);
    VecT v = *(const VecT*)(Clane + (size_t)p.x * F);
    #pragma unroll
    for (int j = 0; j < EPL; j++) acc[j] += c * (float)v[j];
  }

  if constexpr (MODE == 0 || MODE == 1) {
    float ss = 0.f;
    #pragma unroll
    for (int j = 0; j < EPL; j++) {
      acc[j] += bias[lane * EPL + j];
      acc[j] = fmaxf(acc[j], 0.f);
      ss += acc[j] * acc[j];
    }
    float scale = 1.f;
    if constexpr (MODE == 0) {
      #pragma unroll
      for (int off = 32; off > 0; off >>= 1) ss += __shfl_xor(ss, off);
      scale = 1.f / fmaxf(sqrtf(ss), 1e-12f);
    }
    VecT o;
    #pragma unroll
    for (int j = 0; j < EPL; j++) o[j] = (__bf16)(acc[j] * scale);
    *(VecT*)(hout + (size_t)i * F + lane * EPL) = o;
  } else {
    const bool ismu = lane < 32;
    const int cb4 = (ismu ? lane : lane - 32) * 4;
    float v[4];
    #pragma unroll
    for (int j = 0; j < 4; j++) v[j] = acc[j] + (ismu ? bmu[cb4 + j] : blv[cb4 + j]);
    const size_t NZ = (size_t)n * 128;
    float* dstp = ismu ? (zout + NZ + (size_t)i * 128 + cb4)
                       : (zout + 2 * NZ + (size_t)i * 128 + cb4);
    float4 st; st.x = v[0]; st.y = v[1]; st.z = v[2]; st.w = v[3];
    *(float4*)dstp = st;
    float ov[4];
    #pragma unroll
    for (int j = 0; j < 4; j++) ov[j] = __shfl_xor(v[j], 32);
    if (ismu) {
      float4 ev = *(const float4*)(eps + (size_t)i * 128 + cb4);
      float4 zs;
      zs.x = v[0] + ev.x * expf(0.5f * ov[0]);
      zs.y = v[1] + ev.y * expf(0.5f * ov[1]);
      zs.z = v[2] + ev.z * expf(0.5f * ov[2]);
      zs.w = v[3] + ev.w * expf(0.5f * ov[3]);
      *(float4*)(zout + (size_t)i * 128 + cb4) = zs;
    }
  }
}

// ---------------- launch ----------------

extern "C" void kernel_launch(void* const* d_in, const int* in_sizes, int n_in,
                              void* d_out, int out_size, void* d_ws, size_t ws_size,
                              hipStream_t stream) {
  const float* x   = (const float*)d_in[0];
  const int*   ei  = (const int*)d_in[1];
  const float* eps = (const float*)d_in[2];
  const float* W1  = (const float*)d_in[3];
  const float* b1  = (const float*)d_in[4];
  const float* W2  = (const float*)d_in[5];
  const float* b2  = (const float*)d_in[6];
  const float* Wmu = (const float*)d_in[7];
  const float* bmu = (const float*)d_in[8];
  const float* Wlv = (const float*)d_in[9];
  const float* blv = (const float*)d_in[10];
  float* out = (float*)d_out;

  const int N = 20000, E = 320000, D = 512, H = 512, Z = 128;
  const int* src = ei;
  const int* dst = ei + E;

  char* p = (char*)d_ws;
  auto alloc = [&](size_t bytes) { char* r = p; p += (bytes + 255) & ~(size_t)255; return r; };
  int*    cnt      = (int*)alloc((size_t)N * 4);
  int*    cur      = (int*)alloc((size_t)N * 4);
  int*    rowptr   = (int*)alloc((size_t)(N + 1) * 4);
  float*  dinv     = (float*)alloc((size_t)N * 4);
  int2*   csr_pack = (int2*)alloc((size_t)E * 8);
  __bf16* xb  = (__bf16*)alloc((size_t)N * D * 2);
  __bf16* hb  = (__bf16*)alloc((size_t)N * H * 2);
  __bf16* cb  = (__bf16*)alloc((size_t)N * H * 2);
  __bf16* w1t = (__bf16*)alloc((size_t)D * H * 2);
  __bf16* w2t = (__bf16*)alloc((size_t)H * H * 2);
  __bf16* wct = (__bf16*)alloc((size_t)2 * Z * H * 2);

  hipMemsetAsync(cnt, 0, (size_t)N * 4, stream);
  hipMemsetAsync(cur, 0, (size_t)N * 4, stream);

  count_kernel<<<1250, 256, 0, stream>>>(dst, cnt, E);
  dinv_kernel<<<(N + 255) / 256, 256, 0, stream>>>(cnt, dinv, N);
  scan_kernel<<<1, 1024, 0, stream>>>(cnt, rowptr, N);
  fill_kernel<<<1250, 256, 0, stream>>>(src, dst, rowptr, cur, dinv, csr_pack, E);

  f32_to_bf16_k<<<4096, 256, 0, stream>>>(x, xb, (long)N * D / 4);
  weights_prep<<<2560, 256, 0, stream>>>(W1, W2, Wmu, Wlv, w1t, w2t, wct);

  // layer 1
  gemm_bt<<<((N + 127) / 128) * (H / 128), 256, 0, stream>>>(xb, w1t, cb, N, H, D, H / 128);
  prop_kernel<8, 0><<<2500, 512, 0, stream>>>(cb, rowptr, csr_pack, dinv,
                                              b1, nullptr, nullptr, nullptr, hb, nullptr, N);
  // layer 2
  gemm_bt<<<((N + 127) / 128) * (H / 128), 256, 0, stream>>>(hb, w2t, cb, N, H, H, H / 128);
  prop_kernel<8, 1><<<2500, 512, 0, stream>>>(cb, rowptr, csr_pack, dinv,
                                              b2, nullptr, nullptr, nullptr, xb, nullptr, N);
  // heads (mu || lv) + reparameterize
  gemm_bt<<<((N + 127) / 128) * ((2 * Z) / 128), 256, 0, stream>>>(xb, wct, cb, N, 2 * Z, H, (2 * Z) / 128);
  prop_kernel<4, 2><<<2500, 512, 0, stream>>>(cb, rowptr, csr_pack, dinv,
                                              nullptr, bmu, blv, eps, nullptr, out, N);
}

// Round 4
// 231.740 us; speedup vs baseline: 1.1877x; 1.1877x over previous
//
#include <hip/hip_runtime.h>

typedef __bf16 bf16x8 __attribute__((ext_vector_type(8)));
typedef __bf16 bf16x4 __attribute__((ext_vector_type(4)));
typedef float  f32x4  __attribute__((ext_vector_type(4)));
typedef float  f32x2  __attribute__((ext_vector_type(2)));

#define GLDS16(g, l) __builtin_amdgcn_global_load_lds( \
    (const __attribute__((address_space(1))) void*)(g), \
    (__attribute__((address_space(3))) void*)(l), 16, 0, 0)

// fp8 e4m3 (OCP on gfx950) helpers. cb holds 64*y in fp8; the 1/64 is folded
// into the propagation coefficients.
#define FP8_SCALE 64.0f
#define FP8_INV   (1.0f / 64.0f)

__device__ __forceinline__ unsigned char fp8_of_f32(float v) {
  return (unsigned char)(__builtin_amdgcn_cvt_pk_fp8_f32(v, v, 0, false) & 0xff);
}
__device__ __forceinline__ void dec4(unsigned int u, float* o) {
  f32x2 lo = __builtin_amdgcn_cvt_pk_f32_fp8(u, false);
  f32x2 hi = __builtin_amdgcn_cvt_pk_f32_fp8(u, true);
  o[0] = lo[0]; o[1] = lo[1]; o[2] = hi[0]; o[3] = hi[1];
}

// ---------------- graph prep ----------------

__global__ void count_kernel(const int* __restrict__ dst, int* __restrict__ cnt, int E) {
  int idx = blockIdx.x * blockDim.x + threadIdx.x;
  int stride = gridDim.x * blockDim.x;
  for (int e = idx; e < E; e += stride) atomicAdd(&cnt[dst[e]], 1);
}

__global__ void dinv_kernel(const int* __restrict__ cnt, float* __restrict__ dinv, int n) {
  int i = blockIdx.x * blockDim.x + threadIdx.x;
  if (i < n) dinv[i] = rsqrtf((float)cnt[i] + 1.0f);
}

__global__ __launch_bounds__(1024) void scan_kernel(const int* __restrict__ cnt,
                                                    int* __restrict__ rowptr, int n) {
  __shared__ int part[1024];
  int t = threadIdx.x;
  int CH = (n + 1023) >> 10;
  int base = t * CH;
  int s = 0;
  for (int j = 0; j < CH; j++) { int k = base + j; if (k < n) s += cnt[k]; }
  part[t] = s;
  __syncthreads();
  for (int off = 1; off < 1024; off <<= 1) {
    int v = (t >= off) ? part[t - off] : 0;
    __syncthreads();
    part[t] += v;
    __syncthreads();
  }
  int run = (t == 0) ? 0 : part[t - 1];
  for (int j = 0; j < CH; j++) { int k = base + j; if (k < n) { rowptr[k] = run; run += cnt[k]; } }
  if (t == 0) rowptr[n] = part[1023];
}

// packed CSR entry: .x = src index, .y = coef bits (coef includes 1/FP8_SCALE)
__global__ void fill_kernel(const int* __restrict__ src, const int* __restrict__ dst,
                            const int* __restrict__ rowptr, int* __restrict__ cur,
                            const float* __restrict__ dinv,
                            int2* __restrict__ csr_pack, int E) {
  int idx = blockIdx.x * blockDim.x + threadIdx.x;
  int stride = gridDim.x * blockDim.x;
  for (int e = idx; e < E; e += stride) {
    int s = src[e], d = dst[e];
    int slot = rowptr[d] + atomicAdd(&cur[d], 1);
    int2 p; p.x = s; p.y = __float_as_int(dinv[s] * dinv[d] * FP8_INV);
    csr_pack[slot] = p;
  }
}

// ---------------- dtype prep ----------------

__global__ void f32_to_bf16_k(const float* __restrict__ in, __bf16* __restrict__ out, long n4) {
  long idx = (long)blockIdx.x * blockDim.x + threadIdx.x;
  long stride = (long)gridDim.x * blockDim.x;
  for (long i = idx; i < n4; i += stride) {
    float4 v = ((const float4*)in)[i];
    bf16x4 b;
    b[0] = (__bf16)v.x; b[1] = (__bf16)v.y; b[2] = (__bf16)v.z; b[3] = (__bf16)v.w;
    ((bf16x4*)out)[i] = b;
  }
}

// merged weight prep: w1t/w2t = transposed 512x512, wct = transposed concat [256][512]
__global__ void weights_prep(const float* __restrict__ W1, const float* __restrict__ W2,
                             const float* __restrict__ Wmu, const float* __restrict__ Wlv,
                             __bf16* __restrict__ w1t, __bf16* __restrict__ w2t,
                             __bf16* __restrict__ wct) {
  int id = blockIdx.x * blockDim.x + threadIdx.x;
  if (id < 262144) {
    int nn = id >> 9, kk = id & 511;
    w1t[id] = (__bf16)W1[kk * 512 + nn];
  } else if (id < 524288) {
    int t = id - 262144;
    int nn = t >> 9, kk = t & 511;
    w2t[t] = (__bf16)W2[kk * 512 + nn];
  } else if (id < 655360) {
    int t = id - 524288;
    int nn = t >> 9, kk = t & 511;       // nn 0..255
    float v = (nn < 128) ? Wmu[kk * 128 + nn] : Wlv[kk * 128 + (nn - 128)];
    wct[t] = (__bf16)v;
  }
}

// ---------------- GEMM: C[M,N] = A[M,K] @ Bt[N,K]^T  (bf16 in, fp8 out) ----------------
// 128x128 tile, BK=64, double-buffered LDS, counted vmcnt(8) across raw barriers.
// XOR granule swizzle both-sides. Bijective XCD chunking on a 1D grid.
// Epilogue: C stored as fp8(64*y) for the gather-bound propagation pass.

__global__ __launch_bounds__(256) void gemm_bt(const __bf16* __restrict__ A,
                                               const __bf16* __restrict__ Bt,
                                               unsigned char* __restrict__ C,
                                               int M, int N, int K, int ntiles_n) {
  __shared__ __align__(16) __bf16 sA[2][128 * 64];
  __shared__ __align__(16) __bf16 sB[2][128 * 64];
  const int nb = gridDim.x;
  const int orig = blockIdx.x;
  const int q = nb >> 3, r = nb & 7;
  const int xcd = orig & 7, sub = orig >> 3;
  const int pos = (xcd < r) ? (xcd * (q + 1) + sub) : (r * (q + 1) + (xcd - r) * q + sub);
  const int m0 = (pos / ntiles_n) * 128, n0 = (pos % ntiles_n) * 128;

  const int tid = threadIdx.x;
  const int wave = tid >> 6, lane = tid & 63;
  const int wr = wave >> 1, wc = wave & 1;
  f32x4 acc[4][4] = {};
  const int srow = lane >> 3;
  const int sg   = (lane & 7) ^ (srow & 7);
  const int nt = K >> 6;

  auto STAGE = [&](int b, int k0) {
    #pragma unroll
    for (int c = 0; c < 4; ++c) {
      int chunk = wave * 4 + c;
      int row = chunk * 8 + srow;
      int ga = m0 + row; if (ga >= M) ga = M - 1;
      GLDS16(A  + (long)ga * K         + k0 + sg * 8, sA[b] + chunk * 512);
      GLDS16(Bt + (long)(n0 + row) * K + k0 + sg * 8, sB[b] + chunk * 512);
    }
  };

  STAGE(0, 0);
  for (int t = 0; t < nt; ++t) {
    const int cur = t & 1;
    if (t + 1 < nt) {
      STAGE(cur ^ 1, (t + 1) << 6);
      asm volatile("s_waitcnt vmcnt(8)" ::: "memory");
    } else {
      asm volatile("s_waitcnt vmcnt(0)" ::: "memory");
    }
    __builtin_amdgcn_s_barrier();
    __builtin_amdgcn_sched_barrier(0);

    const int fr = lane & 15, gbase = lane >> 4;
    bf16x8 af[4][2], bfr[4][2];
    #pragma unroll
    for (int mi = 0; mi < 4; mi++)
      #pragma unroll
      for (int ks = 0; ks < 2; ks++) {
        int row = wr * 64 + mi * 16 + fr;
        int gs = (ks * 4 + gbase) ^ (row & 7);
        af[mi][ks] = *(const bf16x8*)(sA[cur] + row * 64 + gs * 8);
      }
    #pragma unroll
    for (int ni = 0; ni < 4; ni++)
      #pragma unroll
      for (int ks = 0; ks < 2; ks++) {
        int row = wc * 64 + ni * 16 + fr;
        int gs = (ks * 4 + gbase) ^ (row & 7);
        bfr[ni][ks] = *(const bf16x8*)(sB[cur] + row * 64 + gs * 8);
      }
    #pragma unroll
    for (int mi = 0; mi < 4; mi++)
      #pragma unroll
      for (int ni = 0; ni < 4; ni++) {
        acc[mi][ni] = __builtin_amdgcn_mfma_f32_16x16x32_bf16(af[mi][0], bfr[ni][0], acc[mi][ni], 0, 0, 0);
        acc[mi][ni] = __builtin_amdgcn_mfma_f32_16x16x32_bf16(af[mi][1], bfr[ni][1], acc[mi][ni], 0, 0, 0);
      }
    asm volatile("s_waitcnt lgkmcnt(0)" ::: "memory");
    __builtin_amdgcn_sched_barrier(0);
    __builtin_amdgcn_s_barrier();
  }

  const int crow0 = (lane >> 4) * 4, ccol = lane & 15;
  #pragma unroll
  for (int mi = 0; mi < 4; mi++)
    #pragma unroll
    for (int ni = 0; ni < 4; ni++)
      #pragma unroll
      for (int r2 = 0; r2 < 4; r2++) {
        int row = m0 + wr * 64 + mi * 16 + crow0 + r2;
        if (row < M)
          C[(long)row * N + n0 + wc * 64 + ni * 16 + ccol] =
              fp8_of_f32(acc[mi][ni][r2] * FP8_SCALE);
      }
}

// ---------------- propagation: out = agg + self*h + b, fused epilogues ----------------
// Gathers fp8 rows (half the bytes of bf16), f32 accumulate. One wave per node,
// 8-deep batched gather, packed (src,coef) metadata (coef pre-multiplied by 1/64).
// MODE 0: relu + L2-normalize -> bf16 ; MODE 1: relu -> bf16 ; MODE 2: mu/lv/z -> f32

template<int EPL> struct LSel;
template<> struct LSel<8> { typedef uint2 T; };        // 8 fp8 bytes
template<> struct LSel<4> { typedef unsigned int T; }; // 4 fp8 bytes

template<int EPL, int MODE>
__global__ __launch_bounds__(512) void prop_kernel(
    const unsigned char* __restrict__ Cin, const int* __restrict__ rowptr,
    const int2* __restrict__ csr_pack,
    const float* __restrict__ dinv, const float* __restrict__ bias,
    const float* __restrict__ bmu, const float* __restrict__ blv,
    const float* __restrict__ eps,
    __bf16* __restrict__ hout, float* __restrict__ zout, int n) {
  constexpr int F = EPL * 64;                    // bytes per row
  typedef typename LSel<EPL>::T VecT;
  const int lane = threadIdx.x & 63;
  const int i = blockIdx.x * (blockDim.x >> 6) + (threadIdx.x >> 6);
  if (i >= n) return;
  const unsigned char* __restrict__ Clane = Cin + lane * EPL;

  auto decAll = [&](VecT v, float* o) {
    if constexpr (EPL == 8) { dec4(v.x, o); dec4(v.y, o + 4); }
    else                    { dec4(v, o); }
  };

  float acc[EPL];
  {
    const float di = dinv[i];
    const float sc = di * di * FP8_INV;
    VecT v = *(const VecT*)(Clane + (size_t)i * F);
    float dv[EPL];
    decAll(v, dv);
    #pragma unroll
    for (int j = 0; j < EPL; j++) acc[j] = sc * dv[j];
  }
  int e = rowptr[i];
  const int e1 = rowptr[i + 1];
  for (; e + 8 <= e1; e += 8) {
    int2 p[8];
    #pragma unroll
    for (int q = 0; q < 8; q++) p[q] = csr_pack[e + q];
    VecT v[8];
    #pragma unroll
    for (int q = 0; q < 8; q++) v[q] = *(const VecT*)(Clane + (size_t)p[q].x * F);
    #pragma unroll
    for (int q = 0; q < 8; q++) {
      float c = __int_as_float(p[q].y);
      float dv[EPL];
      decAll(v[q], dv);
      #pragma unroll
      for (int j = 0; j < EPL; j++) acc[j] += c * dv[j];
    }
  }
  for (; e + 4 <= e1; e += 4) {
    int2 p[4];
    #pragma unroll
    for (int q = 0; q < 4; q++) p[q] = csr_pack[e + q];
    VecT v[4];
    #pragma unroll
    for (int q = 0; q < 4; q++) v[q] = *(const VecT*)(Clane + (size_t)p[q].x * F);
    #pragma unroll
    for (int q = 0; q < 4; q++) {
      float c = __int_as_float(p[q].y);
      float dv[EPL];
      decAll(v[q], dv);
      #pragma unroll
      for (int j = 0; j < EPL; j++) acc[j] += c * dv[j];
    }
  }
  for (; e < e1; ++e) {
    int2 p = csr_pack[e];
    float c = __int_as_float(p.y);
    VecT v = *(const VecT*)(Clane + (size_t)p.x * F);
    float dv[EPL];
    decAll(v, dv);
    #pragma unroll
    for (int j = 0; j < EPL; j++) acc[j] += c * dv[j];
  }

  if constexpr (MODE == 0 || MODE == 1) {
    float ss = 0.f;
    #pragma unroll
    for (int j = 0; j < EPL; j++) {
      acc[j] += bias[lane * EPL + j];
      acc[j] = fmaxf(acc[j], 0.f);
      ss += acc[j] * acc[j];
    }
    float scale = 1.f;
    if constexpr (MODE == 0) {
      #pragma unroll
      for (int off = 32; off > 0; off >>= 1) ss += __shfl_xor(ss, off);
      scale = 1.f / fmaxf(sqrtf(ss), 1e-12f);
    }
    bf16x8 o;
    #pragma unroll
    for (int j = 0; j < EPL; j++) o[j] = (__bf16)(acc[j] * scale);
    *(bf16x8*)(hout + (size_t)i * 512 + lane * EPL) = o;
  } else {
    const bool ismu = lane < 32;
    const int cb4 = (ismu ? lane : lane - 32) * 4;
    float v[4];
    #pragma unroll
    for (int j = 0; j < 4; j++) v[j] = acc[j] + (ismu ? bmu[cb4 + j] : blv[cb4 + j]);
    const size_t NZ = (size_t)n * 128;
    float* dstp = ismu ? (zout + NZ + (size_t)i * 128 + cb4)
                       : (zout + 2 * NZ + (size_t)i * 128 + cb4);
    float4 st; st.x = v[0]; st.y = v[1]; st.z = v[2]; st.w = v[3];
    *(float4*)dstp = st;
    float ov[4];
    #pragma unroll
    for (int j = 0; j < 4; j++) ov[j] = __shfl_xor(v[j], 32);
    if (ismu) {
      float4 ev = *(const float4*)(eps + (size_t)i * 128 + cb4);
      float4 zs;
      zs.x = v[0] + ev.x * expf(0.5f * ov[0]);
      zs.y = v[1] + ev.y * expf(0.5f * ov[1]);
      zs.z = v[2] + ev.z * expf(0.5f * ov[2]);
      zs.w = v[3] + ev.w * expf(0.5f * ov[3]);
      *(float4*)(zout + (size_t)i * 128 + cb4) = zs;
    }
  }
}

// ---------------- launch ----------------

extern "C" void kernel_launch(void* const* d_in, const int* in_sizes, int n_in,
                              void* d_out, int out_size, void* d_ws, size_t ws_size,
                              hipStream_t stream) {
  const float* x   = (const float*)d_in[0];
  const int*   ei  = (const int*)d_in[1];
  const float* eps = (const float*)d_in[2];
  const float* W1  = (const float*)d_in[3];
  const float* b1  = (const float*)d_in[4];
  const float* W2  = (const float*)d_in[5];
  const float* b2  = (const float*)d_in[6];
  const float* Wmu = (const float*)d_in[7];
  const float* bmu = (const float*)d_in[8];
  const float* Wlv = (const float*)d_in[9];
  const float* blv = (const float*)d_in[10];
  float* out = (float*)d_out;

  const int N = 20000, E = 320000, D = 512, H = 512, Z = 128;
  const int* src = ei;
  const int* dst = ei + E;

  char* p = (char*)d_ws;
  auto alloc = [&](size_t bytes) { char* r = p; p += (bytes + 255) & ~(size_t)255; return r; };
  int*    cnt      = (int*)alloc((size_t)N * 4);
  int*    cur      = (int*)alloc((size_t)N * 4);
  int*    rowptr   = (int*)alloc((size_t)(N + 1) * 4);
  float*  dinv     = (float*)alloc((size_t)N * 4);
  int2*   csr_pack = (int2*)alloc((size_t)E * 8);
  __bf16* xb  = (__bf16*)alloc((size_t)N * D * 2);
  __bf16* hb  = (__bf16*)alloc((size_t)N * H * 2);
  unsigned char* cb = (unsigned char*)alloc((size_t)N * H);   // fp8 pre-activations
  __bf16* w1t = (__bf16*)alloc((size_t)D * H * 2);
  __bf16* w2t = (__bf16*)alloc((size_t)H * H * 2);
  __bf16* wct = (__bf16*)alloc((size_t)2 * Z * H * 2);

  hipMemsetAsync(cnt, 0, (size_t)N * 4, stream);
  hipMemsetAsync(cur, 0, (size_t)N * 4, stream);

  count_kernel<<<1250, 256, 0, stream>>>(dst, cnt, E);
  dinv_kernel<<<(N + 255) / 256, 256, 0, stream>>>(cnt, dinv, N);
  scan_kernel<<<1, 1024, 0, stream>>>(cnt, rowptr, N);
  fill_kernel<<<1250, 256, 0, stream>>>(src, dst, rowptr, cur, dinv, csr_pack, E);

  f32_to_bf16_k<<<4096, 256, 0, stream>>>(x, xb, (long)N * D / 4);
  weights_prep<<<2560, 256, 0, stream>>>(W1, W2, Wmu, Wlv, w1t, w2t, wct);

  // layer 1
  gemm_bt<<<((N + 127) / 128) * (H / 128), 256, 0, stream>>>(xb, w1t, cb, N, H, D, H / 128);
  prop_kernel<8, 0><<<2500, 512, 0, stream>>>(cb, rowptr, csr_pack, dinv,
                                              b1, nullptr, nullptr, nullptr, hb, nullptr, N);
  // layer 2
  gemm_bt<<<((N + 127) / 128) * (H / 128), 256, 0, stream>>>(hb, w2t, cb, N, H, H, H / 128);
  prop_kernel<8, 1><<<2500, 512, 0, stream>>>(cb, rowptr, csr_pack, dinv,
                                              b2, nullptr, nullptr, nullptr, xb, nullptr, N);
  // heads (mu || lv) + reparameterize
  gemm_bt<<<((N + 127) / 128) * ((2 * Z) / 128), 256, 0, stream>>>(xb, wct, cb, N, 2 * Z, H, (2 * Z) / 128);
  prop_kernel<4, 2><<<2500, 512, 0, stream>>>(cb, rowptr, csr_pack, dinv,
                                              nullptr, bmu, blv, eps, nullptr, out, N);
}